// Round 6
// baseline (166.470 us; speedup 1.0000x reference)
//
#include <hip/hip_runtime.h>
#include <math.h>

#define NQ    12
#define DIM   4096
#define BATCH 512
#define NBLK  1024     // 512 elements x 2 halves
#define NTHR  128

// float2-granular padded LDS index: +2 float2 per 16. Verified conflict-free
// (min bank cycles) for all three exchange patterns at 128 threads.
#define PAD2(i) ((i) + 2 * ((i) >> 4))

// One butterfly level over the 16 register-resident float2 amplitudes.
// Gate q from LDS; J = local register bit.
#define LEVEL(q, J) do {                                                    \
    const float4 GA = *(const float4*)&g[q][0];                             \
    const float4 GB = *(const float4*)&g[q][4];                             \
    _Pragma("unroll")                                                       \
    for (int p = 0; p < 8; ++p) {                                           \
        const int r0 = ((p >> (J)) << ((J) + 1)) | (p & ((1 << (J)) - 1));  \
        const int r1 = r0 | (1 << (J));                                     \
        const float ar = x[r0].x, ai = x[r0].y;                             \
        const float br = x[r1].x, bi = x[r1].y;                             \
        x[r0].x = GA.x * ar - GA.y * ai + GA.z * br - GA.w * bi;            \
        x[r0].y = GA.x * ai + GA.y * ar + GA.z * bi + GA.w * br;            \
        x[r1].x = GB.x * ar - GB.y * ai + GB.z * br - GB.w * bi;            \
        x[r1].y = GB.x * ai + GB.y * ar + GB.z * bi + GB.w * br;            \
    }                                                                       \
} while (0)

__global__ __launch_bounds__(NTHR, 4) void u3_two_phase(
    const float* __restrict__ thetas,   // [12,3]
    const float* __restrict__ sre,      // [512,4096]
    const float* __restrict__ sim_,     // [512,4096]
    float*       __restrict__ out,      // [512,4096,2]
    unsigned*    __restrict__ ctr)      // barrier counter (zeroed per launch)
{
    __shared__ __align__(16) float2 L[2304];    // PAD2(2047)+1 = 2302
    __shared__ __align__(16) float  g[NQ][8];

    const int b = blockIdx.x;
    const int e = b & (BATCH - 1);      // element
    const int h = b >> 9;               // half (state bit 11)
    const int t = threadIdx.x;          // 0..127

    const size_t base = (size_t)e * DIM + (size_t)h * 2048;

    // ---- issue global loads first ----
    const float4* pre = (const float4*)(sre  + base) + 4 * t;
    const float4* pim = (const float4*)(sim_ + base) + 4 * t;
    float4 vr0 = pre[0], vr1 = pre[1], vr2 = pre[2], vr3 = pre[3];
    float4 vi0 = pim[0], vi1 = pim[1], vi2 = pim[2], vi3 = pim[3];

    // ---- gates (threads 0..11); gate q acts on state bit (11-q) ----
    if (t < NQ) {
        float th = thetas[t * 3 + 0];
        float ph = thetas[t * 3 + 1];
        float la = thetas[t * 3 + 2];
        float c, s, cl, sl, cp, sp;
        __sincosf(th * 0.5f, &s, &c);
        __sincosf(la, &sl, &cl);
        __sincosf(ph, &sp, &cp);
        g[t][0] = c;        g[t][1] = 0.0f;
        g[t][2] = -cl * s;  g[t][3] = -sl * s;
        g[t][4] = cp * s;   g[t][5] = sp * s;
        g[t][6] = (cp * cl - sp * sl) * c;
        g[t][7] = (sp * cl + cp * sl) * c;
    }
    __syncthreads();    // gates visible

    // ---- unpack: thread t owns local idx = (t<<4)|r, bits 3:0 in regs ----
    float2 x[16];
    x[ 0] = make_float2(vr0.x, vi0.x); x[ 1] = make_float2(vr0.y, vi0.y);
    x[ 2] = make_float2(vr0.z, vi0.z); x[ 3] = make_float2(vr0.w, vi0.w);
    x[ 4] = make_float2(vr1.x, vi1.x); x[ 5] = make_float2(vr1.y, vi1.y);
    x[ 6] = make_float2(vr1.z, vi1.z); x[ 7] = make_float2(vr1.w, vi1.w);
    x[ 8] = make_float2(vr2.x, vi2.x); x[ 9] = make_float2(vr2.y, vi2.y);
    x[10] = make_float2(vr2.z, vi2.z); x[11] = make_float2(vr2.w, vi2.w);
    x[12] = make_float2(vr3.x, vi3.x); x[13] = make_float2(vr3.y, vi3.y);
    x[14] = make_float2(vr3.z, vi3.z); x[15] = make_float2(vr3.w, vi3.w);

    // ---- stage A: local bits 0..3 -> gates 11,10,9,8 ----
    LEVEL(11, 0); LEVEL(10, 1); LEVEL(9, 2); LEVEL(8, 3);

    // ---- exchange 1: b128 contiguous write; read -> regs = bits 7:4 ----
#pragma unroll
    for (int k = 0; k < 8; ++k) {
        *(float4*)&L[PAD2((t << 4) | (2 * k))] =
            make_float4(x[2 * k].x, x[2 * k].y, x[2 * k + 1].x, x[2 * k + 1].y);
    }
    __syncthreads();
    const int base1 = ((t & 0x70) << 4) | (t & 15);   // bits 10:8 | 3:0
#pragma unroll
    for (int r = 0; r < 16; ++r) x[r] = L[PAD2(base1 | (r << 4))];

    // ---- stage B: bits 4..7 -> gates 7,6,5,4 ----
    LEVEL(7, 0); LEVEL(6, 1); LEVEL(5, 2); LEVEL(4, 3);

    // ---- exchange 2: same-slot writeback (no WAR), read -> regs = bits 10:7
#pragma unroll
    for (int r = 0; r < 16; ++r) L[PAD2(base1 | (r << 4))] = x[r];
    __syncthreads();
#pragma unroll
    for (int r = 0; r < 16; ++r) x[r] = L[PAD2((r << 7) | t)];

    // ---- stage C: reg bits 1,2,3 = idx bits 8,9,10 -> gates 3,2,1 ----
    LEVEL(3, 1); LEVEL(2, 2); LEVEL(1, 3);

    // ---- phase-1 store (NOT nontemporal: keep in L2 for phase 2) ----
    {
        float2* o2 = (float2*)out;
#pragma unroll
        for (int r = 0; r < 16; ++r) o2[base + ((r << 7) | t)] = x[r];
    }

    // ---- device-wide barrier ----
    __threadfence();
    __syncthreads();
    if (t == 0) {
        __hip_atomic_fetch_add(ctr, 1u, __ATOMIC_ACQ_REL, __HIP_MEMORY_SCOPE_AGENT);
        while (__hip_atomic_load(ctr, __ATOMIC_ACQUIRE, __HIP_MEMORY_SCOPE_AGENT) < NBLK)
            __builtin_amdgcn_s_sleep(2);
    }
    __syncthreads();

    // ---- phase 2: bit-11 butterfly (gate 0), in place on out ----
    {
        const float4 GA = *(const float4*)&g[0][0];
        const float4 GB = *(const float4*)&g[0][4];
        float4* O4 = (float4*)out;                       // 2 amps per float4
        const size_t eb4 = (size_t)e * 2048 + (size_t)h * 512;
#pragma unroll
        for (int w = 0; w < 4; ++w) {
            const size_t lo = eb4 + w * NTHR + t;
            float4 Lv = O4[lo];
            float4 Hv = O4[lo + 1024];
            float4 Lo, Hi;
            Lo.x = GA.x * Lv.x - GA.y * Lv.y + GA.z * Hv.x - GA.w * Hv.y;
            Lo.y = GA.x * Lv.y + GA.y * Lv.x + GA.z * Hv.y + GA.w * Hv.x;
            Lo.z = GA.x * Lv.z - GA.y * Lv.w + GA.z * Hv.z - GA.w * Hv.w;
            Lo.w = GA.x * Lv.w + GA.y * Lv.z + GA.z * Hv.w + GA.w * Hv.z;
            Hi.x = GB.x * Lv.x - GB.y * Lv.y + GB.z * Hv.x - GB.w * Hv.y;
            Hi.y = GB.x * Lv.y + GB.y * Lv.x + GB.z * Hv.y + GB.w * Hv.x;
            Hi.z = GB.x * Lv.z - GB.y * Lv.w + GB.z * Hv.z - GB.w * Hv.w;
            Hi.w = GB.x * Lv.w + GB.y * Lv.z + GB.z * Hv.w + GB.w * Hv.z;
            O4[lo]        = Lo;
            O4[lo + 1024] = Hi;
        }
    }
}

extern "C" void kernel_launch(void* const* d_in, const int* in_sizes, int n_in,
                              void* d_out, int out_size, void* d_ws, size_t ws_size,
                              hipStream_t stream) {
    const float* thetas = (const float*)d_in[0];
    const float* sre    = (const float*)d_in[1];
    const float* sim_   = (const float*)d_in[2];
    float* out = (float*)d_out;
    unsigned* ctr = (unsigned*)d_ws;

    // zero the barrier counter every call (graph-capture-safe, deterministic)
    hipMemsetAsync(ctr, 0, 4, stream);
    u3_two_phase<<<NBLK, NTHR, 0, stream>>>(thetas, sre, sim_, out, ctr);
}

// Round 7
// 20.003 us; speedup vs baseline: 8.3221x; 8.3221x over previous
//
#include <hip/hip_runtime.h>
#include <math.h>

#define NQ    12
#define DIM   4096
#define HALF  2048
#define BATCH 512
#define NBLK  1024     // 2 blocks per element (one per bit-11 half)
#define NTHR  128

// float2-granular padded LDS index: +2 float2 per 16. Verified conflict-free
// (min bank cycles) for all exchange patterns at 128 threads / 2 waves.
#define PAD2(i) ((i) + 2 * ((i) >> 4))

// One butterfly level over the 16 register-resident float2 amplitudes.
#define LEVEL(q, J) do {                                                    \
    const float4 GA = *(const float4*)&g[q][0];                             \
    const float4 GB = *(const float4*)&g[q][4];                             \
    _Pragma("unroll")                                                       \
    for (int p = 0; p < 8; ++p) {                                           \
        const int r0 = ((p >> (J)) << ((J) + 1)) | (p & ((1 << (J)) - 1));  \
        const int r1 = r0 | (1 << (J));                                     \
        const float ar = x[r0].x, ai = x[r0].y;                             \
        const float br = x[r1].x, bi = x[r1].y;                             \
        x[r0].x = GA.x * ar - GA.y * ai + GA.z * br - GA.w * bi;            \
        x[r0].y = GA.x * ai + GA.y * ar + GA.z * bi + GA.w * br;            \
        x[r1].x = GB.x * ar - GB.y * ai + GB.z * br - GB.w * bi;            \
        x[r1].y = GB.x * ai + GB.y * ar + GB.z * bi + GB.w * br;            \
    }                                                                       \
} while (0)

// bit-11 combine at load time: x = (P.x+iP.y)*lo + (P.z+iP.w)*hi
#define CMB1(lrc, lic, hrc, hic) make_float2(                               \
    P.x * (lrc) - P.y * (lic) + P.z * (hrc) - P.w * (hic),                  \
    P.x * (lic) + P.y * (lrc) + P.z * (hic) + P.w * (hrc))

__global__ __launch_bounds__(NTHR) void u3_half_kernel(
    const float* __restrict__ thetas,   // [12,3]
    const float* __restrict__ sre,      // [512,4096]
    const float* __restrict__ sim_,     // [512,4096]
    float*       __restrict__ out)      // [512,4096,2]
{
    __shared__ __align__(16) float2 L[2304];    // PAD2(2047)+1 = 2302
    __shared__ __align__(16) float  g[NQ][8];

    const int b = blockIdx.x;
    const int e = b >> 1;               // element
    const int h = b & 1;                // bit-11 half this block produces
    const int t = threadIdx.x;          // 0..127

    // ---- issue ALL global loads first (both halves of the element) ----
    const float* Sr = sre  + (size_t)e * DIM;
    const float* Si = sim_ + (size_t)e * DIM;
    const float4* plr = (const float4*)Sr + 4 * t;
    const float4* pli = (const float4*)Si + 4 * t;
    const float4* phr = (const float4*)(Sr + HALF) + 4 * t;
    const float4* phi = (const float4*)(Si + HALF) + 4 * t;
    float4 lr0 = plr[0], lr1 = plr[1], lr2 = plr[2], lr3 = plr[3];
    float4 li0 = pli[0], li1 = pli[1], li2 = pli[2], li3 = pli[3];
    float4 hr0 = phr[0], hr1 = phr[1], hr2 = phr[2], hr3 = phr[3];
    float4 hi0 = phi[0], hi1 = phi[1], hi2 = phi[2], hi3 = phi[3];

    // ---- gates (threads 0..11); gate q acts on state bit (11-q) ----
    if (t < NQ) {
        float th = thetas[t * 3 + 0];
        float ph = thetas[t * 3 + 1];
        float la = thetas[t * 3 + 2];
        float c, s, cl, sl, cp, sp;
        __sincosf(th * 0.5f, &s, &c);
        __sincosf(la, &sl, &cl);
        __sincosf(ph, &sp, &cp);
        g[t][0] = c;        g[t][1] = 0.0f;
        g[t][2] = -cl * s;  g[t][3] = -sl * s;
        g[t][4] = cp * s;   g[t][5] = sp * s;
        g[t][6] = (cp * cl - sp * sl) * c;
        g[t][7] = (sp * cl + cp * sl) * c;
    }
    __syncthreads();    // #1: gates visible

    // ---- bit-11 (gate 0) butterfly fused into load: this block keeps
    //      row h of the gate. Thread owns local idx = (t<<4)|r. ----
    const float4 P = *(const float4*)&g[0][4 * h];
    float2 x[16];
    x[ 0] = CMB1(lr0.x, li0.x, hr0.x, hi0.x);
    x[ 1] = CMB1(lr0.y, li0.y, hr0.y, hi0.y);
    x[ 2] = CMB1(lr0.z, li0.z, hr0.z, hi0.z);
    x[ 3] = CMB1(lr0.w, li0.w, hr0.w, hi0.w);
    x[ 4] = CMB1(lr1.x, li1.x, hr1.x, hi1.x);
    x[ 5] = CMB1(lr1.y, li1.y, hr1.y, hi1.y);
    x[ 6] = CMB1(lr1.z, li1.z, hr1.z, hi1.z);
    x[ 7] = CMB1(lr1.w, li1.w, hr1.w, hi1.w);
    x[ 8] = CMB1(lr2.x, li2.x, hr2.x, hi2.x);
    x[ 9] = CMB1(lr2.y, li2.y, hr2.y, hi2.y);
    x[10] = CMB1(lr2.z, li2.z, hr2.z, hi2.z);
    x[11] = CMB1(lr2.w, li2.w, hr2.w, hi2.w);
    x[12] = CMB1(lr3.x, li3.x, hr3.x, hi3.x);
    x[13] = CMB1(lr3.y, li3.y, hr3.y, hi3.y);
    x[14] = CMB1(lr3.z, li3.z, hr3.z, hi3.z);
    x[15] = CMB1(lr3.w, li3.w, hr3.w, hi3.w);

    // ---- stage A: local bits 0..3 -> gates 11,10,9,8 ----
    LEVEL(11, 0); LEVEL(10, 1); LEVEL(9, 2); LEVEL(8, 3);

    // ---- exchange 1: b128 contiguous write; read -> regs = bits 7:4 ----
#pragma unroll
    for (int k = 0; k < 8; ++k) {
        *(float4*)&L[PAD2((t << 4) | (2 * k))] =
            make_float4(x[2 * k].x, x[2 * k].y, x[2 * k + 1].x, x[2 * k + 1].y);
    }
    __syncthreads();    // #2
    const int base1 = ((t & 0x70) << 4) | (t & 15);   // bits 10:8 | 3:0
#pragma unroll
    for (int r = 0; r < 16; ++r) x[r] = L[PAD2(base1 | (r << 4))];

    // ---- stage B: local bits 4..7 -> gates 7,6,5,4 ----
    LEVEL(7, 0); LEVEL(6, 1); LEVEL(5, 2); LEVEL(4, 3);

    // ---- exchange 2: same-slot writeback (no WAR), read -> regs = bits 10:7
#pragma unroll
    for (int r = 0; r < 16; ++r) L[PAD2(base1 | (r << 4))] = x[r];
    __syncthreads();    // #3
#pragma unroll
    for (int r = 0; r < 16; ++r) x[r] = L[PAD2((r << 7) | t)];

    // ---- stage C: local bits 8,9,10 -> gates 3,2,1 (bit 7 done in B) ----
    LEVEL(3, 1); LEVEL(2, 2); LEVEL(1, 3);

    // ---- store: global idx = e*4096 + h*2048 + ((r<<7)|t) ----
    {
        float2* o2 = (float2*)out + (size_t)e * DIM + (size_t)h * HALF;
#pragma unroll
        for (int r = 0; r < 16; ++r) o2[(r << 7) | t] = x[r];
    }
}

extern "C" void kernel_launch(void* const* d_in, const int* in_sizes, int n_in,
                              void* d_out, int out_size, void* d_ws, size_t ws_size,
                              hipStream_t stream) {
    const float* thetas = (const float*)d_in[0];
    const float* sre    = (const float*)d_in[1];
    const float* sim_   = (const float*)d_in[2];
    float* out = (float*)d_out;

    u3_half_kernel<<<NBLK, NTHR, 0, stream>>>(thetas, sre, sim_, out);
}